// Round 1
// baseline (167.522 us; speedup 1.0000x reference)
//
#include <hip/hip_runtime.h>

#define F_ELEMS 2097152            // B*T*H*W = 4*8*256*256
#define IMG 65536                  // H*W

__device__ __forceinline__ float sigm(float x){ return 1.0f/(1.0f + __expf(-x)); }
__device__ __forceinline__ float tanh_fast(float x){
    float t = __expf(2.0f*x);
    return 1.0f - 2.0f/(t + 1.0f);   // saturates correctly at +/-inf
}

__global__ void zero_out(float* out){ out[0] = 0.0f; }

// ---------------------------------------------------------------------------
// K1: direct conv 3x3 (8 -> 64 ch) fused with pointwise nonlinearities.
// grid: (64 tiles, B=4, chunk=4); chunk handles 16 output channels = 2 field
// groups. Tile: 64(W) x 16(H); thread = 4 px along W; 16 oc register-blocked.
// ws fields (float arrays of F_ELEMS): 0 kappa^2, 1 m1, 2 m2, 3 Hxx, 4 Hs,
// 5 Hyy, 6 D, 7 ybuf.
// ---------------------------------------------------------------------------
__global__ __launch_bounds__(256) void conv_pointwise(
    const float* __restrict__ x, const float* __restrict__ w,
    float* __restrict__ ws, float* __restrict__ out)
{
    __shared__ float xs[8*18*68];    // 8 ch, 18 rows, 66 cols padded to 68
    __shared__ float wl[1152];       // [c*9+k][16 oc]
    __shared__ float red[256];

    const int tid   = threadIdx.x;
    const int tix   = blockIdx.x & 3;        // W tile (4)
    const int tiy   = blockIdx.x >> 2;       // H tile (16)
    const int b     = blockIdx.y;
    const int chunk = blockIdx.z;            // oc base = chunk*16

    // ---- stage x tile (with halo) into LDS ----
    const int i0  = tiy*16 - 1;
    const int j0t = tix*64 - 1;
    for (int e = tid; e < 8*18*66; e += 256){
        int c   = e / 1188;                  // 18*66
        int rem = e - c*1188;
        int r   = rem / 66;
        int col = rem - r*66;
        int gi = i0 + r, gj = j0t + col;
        float v = 0.0f;
        if (gi >= 0 && gi < 256 && gj >= 0 && gj < 256)
            v = x[((b*8 + c) << 16) + (gi << 8) + gj];
        xs[c*1224 + r*68 + col] = v;
    }
    // ---- stage this chunk's weights, transposed to [c*9+k][oc16] ----
    for (int e = tid; e < 1152; e += 256){
        int q = e & 15, ck = e >> 4;         // ck = c*9+k in 0..71
        int c = ck / 9, k = ck - c*9;
        wl[ck*16 + q] = w[((chunk*16 + q)*8 + c)*9 + k];
    }
    __syncthreads();

    const int tx = tid & 15, ty = tid >> 4;
    const int i  = tiy*16 + ty;
    const int j0 = tix*64 + (tx << 2);

    float4 acc[16];
    #pragma unroll
    for (int q = 0; q < 16; ++q) acc[q] = make_float4(0.f,0.f,0.f,0.f);

    #pragma unroll
    for (int c = 0; c < 8; ++c){
        #pragma unroll
        for (int dh = 0; dh < 3; ++dh){
            const float* row = &xs[c*1224 + (ty+dh)*68 + (tx<<2)];
            float4 a4 = *(const float4*)row;       // cols tx*4 .. +3 (16B aligned)
            float2 b2 = *(const float2*)(row + 4); // cols +4, +5
            float vv[6] = {a4.x, a4.y, a4.z, a4.w, b2.x, b2.y};
            #pragma unroll
            for (int dw = 0; dw < 3; ++dw){
                const int kb = (c*9 + dh*3 + dw)*16;
                #pragma unroll
                for (int q4 = 0; q4 < 4; ++q4){
                    float4 wv = *(const float4*)&wl[kb + (q4<<2)];
                    const float* wf = (const float*)&wv;
                    #pragma unroll
                    for (int l = 0; l < 4; ++l){
                        const int q = (q4<<2) + l;
                        acc[q].x = fmaf(vv[dw+0], wf[l], acc[q].x);
                        acc[q].y = fmaf(vv[dw+1], wf[l], acc[q].y);
                        acc[q].z = fmaf(vv[dw+2], wf[l], acc[q].z);
                        acc[q].w = fmaf(vv[dw+3], wf[l], acc[q].w);
                    }
                }
            }
        }
    }

    // ---- pointwise nonlinearities + store fields ----
    const int pixbase = (i << 8) + j0;
#define STOR(g,t,v) *reinterpret_cast<float4*>(&ws[(g)*F_ELEMS + ((b*8+(t))<<16) + pixbase]) = (v)

    float ldacc = 0.0f;
    if (chunk == 0){
        #pragma unroll
        for (int t = 0; t < 8; ++t){
            float4 th = acc[t], o;
            float* tp = (float*)&th; float* op = (float*)&o;
            #pragma unroll
            for (int p = 0; p < 4; ++p){ float s = 0.99f*sigm(tp[p]) + 0.01f; op[p] = s*s; }
            STOR(0, t, o);            // kappa^2
            STOR(1, t, acc[t+8]);     // m1 (raw)
        }
    } else if (chunk == 1){
        #pragma unroll
        for (int t = 0; t < 8; ++t){
            STOR(2, t, acc[t]);       // m2 (raw)
            float4 th = acc[t+8], o;
            float* tp = (float*)&th; float* op = (float*)&o;
            #pragma unroll
            for (int p = 0; p < 4; ++p) op[p] = 0.99f*sigm(tp[p]) + 0.01f;
            STOR(3, t, o);            // Hxx
        }
    } else if (chunk == 2){
        #pragma unroll
        for (int t = 0; t < 8; ++t){
            float4 ha = acc[t], hb = acc[t+8], o;
            float* ap = (float*)&ha; float* bp = (float*)&hb; float* op = (float*)&o;
            #pragma unroll
            for (int p = 0; p < 4; ++p)
                op[p] = 0.1f*(tanh_fast(ap[p]) + tanh_fast(bp[p]));
            STOR(4, t, o);            // Hs = Hxy + Hyx
        }
    } else {
        #pragma unroll
        for (int t = 0; t < 8; ++t){
            float4 th = acc[t], o;
            float* tp = (float*)&th; float* op = (float*)&o;
            #pragma unroll
            for (int p = 0; p < 4; ++p) op[p] = 0.99f*sigm(tp[p]) + 0.01f;
            STOR(5, t, o);            // Hyy
            float4 ta = acc[t+8], od;
            float* tap = (float*)&ta; float* odp = (float*)&od;
            #pragma unroll
            for (int p = 0; p < 4; ++p){
                float tau = 9.9f*sigm(tap[p]) + 0.1f;
                odp[p] = 1.0f/(tau*tau);          // D = dt/tau^2, dt=1
                ldacc  += -2.0f*__logf(tau);      // log D
            }
            STOR(6, t, od);           // D
        }
    }
#undef STOR

    if (chunk == 3){
        red[tid] = ldacc;
        __syncthreads();
        for (int s = 128; s > 0; s >>= 1){
            if (tid < s) red[tid] += red[tid + s];
            __syncthreads();
        }
        if (tid == 0) atomicAdd(out, -0.5f*red[0]);   // -0.5*logdetD partial
    }
}

// ---------------------------------------------------------------------------
// A(u): spatially-varying 9-point stencil.
// ---------------------------------------------------------------------------
__device__ __forceinline__ void row6(const float* __restrict__ u, int rb, int j0, float v[6]){
    const float4 c4 = *(const float4*)&u[rb + j0];
    v[1] = c4.x; v[2] = c4.y; v[3] = c4.z; v[4] = c4.w;
    v[0] = (j0 > 0)   ? u[rb + j0 - 1] : 0.0f;
    v[5] = (j0 < 252) ? u[rb + j0 + 4] : 0.0f;
}

__device__ __forceinline__ float4 applyA(const float* __restrict__ u,
    const float* __restrict__ ws, int lin, int i, int j0)
{
    float vc[6], vn[6], vs[6];
    const int rb = lin - j0;
    row6(u, rb, j0, vc);
    if (i < 255) row6(u, rb + 256, j0, vn);
    else { vn[0]=vn[1]=vn[2]=vn[3]=vn[4]=vn[5]=0.0f; }
    if (i > 0) row6(u, rb - 256, j0, vs);
    else { vs[0]=vs[1]=vs[2]=vs[3]=vs[4]=vs[5]=0.0f; }

    float4 k2v = *(const float4*)&ws[0*F_ELEMS + lin];
    float4 m1v = *(const float4*)&ws[1*F_ELEMS + lin];
    float4 m2v = *(const float4*)&ws[2*F_ELEMS + lin];
    float4 hxv = *(const float4*)&ws[3*F_ELEMS + lin];
    float4 hsv = *(const float4*)&ws[4*F_ELEMS + lin];
    float4 hyv = *(const float4*)&ws[5*F_ELEMS + lin];
    const float* k2p = (const float*)&k2v;
    const float* m1p = (const float*)&m1v;
    const float* m2p = (const float*)&m2v;
    const float* hxp = (const float*)&hxv;
    const float* hsp = (const float*)&hsv;
    const float* hyp = (const float*)&hyv;

    float4 r;
    float* rp = (float*)&r;
    #pragma unroll
    for (int p = 0; p < 4; ++p){
        float hxx = hxp[p], hyy = hyp[p];
        rp[p] = (k2p[p] + 2.0f*(hxx + hyy))*vc[p+1]
              + (0.5f*m1p[p] - hxx)*vc[p+2]
              - (0.5f*m1p[p] + hxx)*vc[p]
              + (0.5f*m2p[p] - hyy)*vn[p+1]
              - (0.5f*m2p[p] + hyy)*vs[p+1]
              - 0.25f*hsp[p]*(vn[p+2] - vs[p+2] - vn[p] + vs[p]);
    }
    return r;
}

// K2: y = A(x) -> ws[7F]
__global__ __launch_bounds__(256) void stepA1(const float* __restrict__ x,
                                              float* __restrict__ ws)
{
    const int gid = blockIdx.x*256 + threadIdx.x;
    const int lin = gid << 2;
    const int j0  = lin & 255;
    const int i   = (lin >> 8) & 255;
    float4 y = applyA(x, ws, lin, i, j0);
    *(float4*)&ws[7*F_ELEMS + lin] = y;
}

// K3: z = A(y); r = x + z - x_prev; accumulate 0.5 * sum(D r^2)
__global__ __launch_bounds__(256) void stepA2(const float* __restrict__ x,
                                              const float* __restrict__ ws,
                                              float* __restrict__ out)
{
    __shared__ float red[256];
    const int tid = threadIdx.x;
    const int gid = blockIdx.x*256 + tid;
    const int lin = gid << 2;
    const int j0  = lin & 255;
    const int i   = (lin >> 8) & 255;
    const int t   = (lin >> 16) & 7;

    float4 z = applyA(&ws[7*F_ELEMS], ws, lin, i, j0);
    float4 xc = *(const float4*)&x[lin];
    float4 xp = make_float4(0.f,0.f,0.f,0.f);
    if (t > 0) xp = *(const float4*)&x[lin - IMG];
    float4 Dv = *(const float4*)&ws[6*F_ELEMS + lin];

    const float* zp = (const float*)&z;
    const float* xcp = (const float*)&xc;
    const float* xpp = (const float*)&xp;
    const float* dp  = (const float*)&Dv;
    float local = 0.0f;
    #pragma unroll
    for (int p = 0; p < 4; ++p){
        float r = xcp[p] + zp[p] - xpp[p];   // Mx - x_prev, dt=1
        local += dp[p]*r*r;
    }

    red[tid] = local;
    __syncthreads();
    for (int s = 128; s > 0; s >>= 1){
        if (tid < s) red[tid] += red[tid + s];
        __syncthreads();
    }
    if (tid == 0) atomicAdd(out, 0.5f*red[0]);
}

extern "C" void kernel_launch(void* const* d_in, const int* in_sizes, int n_in,
                              void* d_out, int out_size, void* d_ws, size_t ws_size,
                              hipStream_t stream)
{
    const float* x = (const float*)d_in[0];
    const float* w = (const float*)d_in[1];
    float* out = (float*)d_out;
    float* ws  = (float*)d_ws;

    zero_out<<<1, 1, 0, stream>>>(out);
    conv_pointwise<<<dim3(64, 4, 4), 256, 0, stream>>>(x, w, ws, out);
    stepA1<<<2048, 256, 0, stream>>>(x, ws);
    stepA2<<<2048, 256, 0, stream>>>(x, ws, out);
}

// Round 2
// 108.480 us; speedup vs baseline: 1.5443x; 1.5443x over previous
//
#include <hip/hip_runtime.h>

#define F_ELEMS 2097152            // B*T*H*W = 4*8*256*256 (elements per field)
#define IMG 65536                  // H*W

typedef _Float16 half8  __attribute__((ext_vector_type(8)));
typedef _Float16 half2v __attribute__((ext_vector_type(2)));
typedef _Float16 half4v __attribute__((ext_vector_type(4)));
typedef float    floatx4 __attribute__((ext_vector_type(4)));

__device__ __forceinline__ float sigm(float x){ return 1.0f/(1.0f + __expf(-x)); }
__device__ __forceinline__ float tanh_fast(float x){
    float t = __expf(2.0f*x);
    return 1.0f - 2.0f/(t + 1.0f);
}

__global__ void zero_out(float* out){ out[0] = 0.0f; }

// ---------------------------------------------------------------------------
// K1: conv 3x3 (8ch -> 64ch) via MFMA f16 implicit GEMM, fused pointwise.
// Block: strip of 2 rows x 256 cols for one b; computes all 64 oc.
// K decomposition: MFMA 16x16x32: K=32 = 4 taps x 8 input channels.
// xt LDS layout [row][col][c] (channel-interleaved, 16B/pixel) -> B-frag is
// one ds_read_b128. Weights Wl[t][oc][c], taps 9..11 zero-padded.
// Fields stored f16: 0 kappa^2, 1 m1, 2 m2, 3 Hxx, 4 Hs, 5 Hyy, 6 D.
// ---------------------------------------------------------------------------
__global__ __launch_bounds__(256) void conv_mfma(
    const float* __restrict__ x, const float* __restrict__ w,
    _Float16* __restrict__ fld, float* __restrict__ out)
{
    __shared__ _Float16 xt[4*258*8];     // 4 rows, 258 cols (halo), 8 ch
    __shared__ _Float16 Wl[12*64*8];     // [tap][oc][c]
    __shared__ float red[256];

    const int tid = threadIdx.x;
    const int i0  = blockIdx.x << 1;     // strip of 2 rows
    const int b   = blockIdx.y;

    // ---- stage x (f32 -> f16, channel pairs for 4B LDS writes) ----
    for (int e = tid; e < 258*4*4; e += 256){
        int cc = e % 258;
        int rr = (e/258) & 3;
        int cp = e / (258*4);            // channel pair 0..3
        int gi = i0 - 1 + rr, gj = cc - 1;
        float v0 = 0.0f, v1 = 0.0f;
        if (gi >= 0 && gi < 256 && gj >= 0 && gj < 256){
            int base = ((b*8 + 2*cp) << 16) + (gi << 8) + gj;
            v0 = x[base];
            v1 = x[base + IMG];
        }
        half2v h; h[0] = (_Float16)v0; h[1] = (_Float16)v1;
        *(half2v*)&xt[(rr*258 + cc)*8 + 2*cp] = h;
    }
    // ---- stage weights [tap][oc][c], zero-pad taps 9..11 ----
    for (int e = tid; e < 12*64*8; e += 256){
        int c  = e & 7;
        int oc = (e >> 3) & 63;
        int t  = e >> 9;
        float v = (t < 9) ? w[(oc*8 + c)*9 + t] : 0.0f;
        Wl[e] = (_Float16)v;             // e == (t*64+oc)*8 + c
    }
    __syncthreads();

    const int lane = tid & 63;
    const int quad = lane >> 4;
    const int l16  = lane & 15;
    const int wv   = tid >> 6;

    // A-frags: A[m=oc_local][k=quad*8+j] -> Wl[tap=s*4+quad][ot*16+l16][0..7]
    half8 afr[4][3];
    int boff[3];
    #pragma unroll
    for (int s = 0; s < 3; ++s){
        int t  = s*4 + quad;
        afr[0][s] = *(const half8*)&Wl[(t*64 +  0 + l16)*8];
        afr[1][s] = *(const half8*)&Wl[(t*64 + 16 + l16)*8];
        afr[2][s] = *(const half8*)&Wl[(t*64 + 32 + l16)*8];
        afr[3][s] = *(const half8*)&Wl[(t*64 + 48 + l16)*8];
        int tc = (t < 9) ? t : 8;        // taps >=9 have zero weights
        int dh = tc / 3, dw = tc - dh*3;
        boff[s] = (dh*258 + dw)*8;
    }

    float ldacc = 0.0f;

    // 32 groups of 16 px (2 rows x 16 col-groups); 8 iters per wave
    #pragma unroll 2
    for (int it = 0; it < 8; ++it){
        const int g   = it*4 + wv;
        const int r   = g >> 4;
        const int jb  = ((g & 15) << 4) + l16;   // image col of this lane's px
        const int xoff = (r*258 + jb)*8;

        floatx4 acc0 = {0,0,0,0}, acc1 = {0,0,0,0}, acc2 = {0,0,0,0}, acc3 = {0,0,0,0};
        #pragma unroll
        for (int s = 0; s < 3; ++s){
            half8 bf = *(const half8*)&xt[xoff + boff[s]];
            acc0 = __builtin_amdgcn_mfma_f32_16x16x32_f16(afr[0][s], bf, acc0, 0, 0, 0);
            acc1 = __builtin_amdgcn_mfma_f32_16x16x32_f16(afr[1][s], bf, acc1, 0, 0, 0);
            acc2 = __builtin_amdgcn_mfma_f32_16x16x32_f16(afr[2][s], bf, acc2, 0, 0, 0);
            acc3 = __builtin_amdgcn_mfma_f32_16x16x32_f16(afr[3][s], bf, acc3, 0, 0, 0);
        }

        // epilogue: lane holds oc = ot*16 + quad*4 + reg, px col = jb, row i0+r
        const int pix0 = (b << 19) + ((i0 + r) << 8) + jb;
#define STO(f, tt, v) fld[(f)*F_ELEMS + ((tt) << 16) + pix0] = (_Float16)(v)
        // ot=0: g0 kappa (quads 0,1) / g1 m1 (quads 2,3)
        #pragma unroll
        for (int rg = 0; rg < 4; ++rg){
            int oc = quad*4 + rg, tt = oc & 7;
            float v = acc0[rg];
            if (oc < 8){ float s = 0.99f*sigm(v) + 0.01f; STO(0, tt, s*s); }
            else       { STO(1, tt, v); }
        }
        // ot=1: g2 m2 / g3 Hxx
        #pragma unroll
        for (int rg = 0; rg < 4; ++rg){
            int oc = 16 + quad*4 + rg, tt = oc & 7;
            float v = acc1[rg];
            if (oc < 24){ STO(2, tt, v); }
            else        { STO(3, tt, 0.99f*sigm(v) + 0.01f); }
        }
        // ot=2: g4 Hxy / g5 Hyx -> Hs = 0.1(tanh+tanh), stored by quads 0,1
        #pragma unroll
        for (int rg = 0; rg < 4; ++rg){
            float th    = 0.1f*tanh_fast(acc2[rg]);
            float other = __shfl_xor(th, 32, 64);
            if (quad < 2){
                int tt = quad*4 + rg;            // oc = 32+quad*4+rg, tt = oc&7
                STO(4, tt, th + other);
            }
        }
        // ot=3: g6 Hyy / g7 tau -> D, logdet
        #pragma unroll
        for (int rg = 0; rg < 4; ++rg){
            int oc = 48 + quad*4 + rg, tt = oc & 7;
            float v = acc3[rg];
            if (oc < 56){ STO(5, tt, 0.99f*sigm(v) + 0.01f); }
            else {
                float tau = 9.9f*sigm(v) + 0.1f;
                STO(6, tt, 1.0f/(tau*tau));
                ldacc += __logf(tau);            // -0.5*logdetD == +sum(log tau)
            }
        }
#undef STO
    }

    red[tid] = ldacc;
    __syncthreads();
    for (int s = 128; s > 0; s >>= 1){
        if (tid < s) red[tid] += red[tid + s];
        __syncthreads();
    }
    if (tid == 0) atomicAdd(out, red[0]);
}

// ---------------------------------------------------------------------------
// A(u) with f16 coefficient fields.
// ---------------------------------------------------------------------------
__device__ __forceinline__ void ldf4(const _Float16* __restrict__ p, float o[4]){
    half4v h = *(const half4v*)p;
    o[0] = (float)h[0]; o[1] = (float)h[1]; o[2] = (float)h[2]; o[3] = (float)h[3];
}

__device__ __forceinline__ void row6(const float* __restrict__ u, int rb, int j0, float v[6]){
    const float4 c4 = *(const float4*)&u[rb + j0];
    v[1] = c4.x; v[2] = c4.y; v[3] = c4.z; v[4] = c4.w;
    v[0] = (j0 > 0)   ? u[rb + j0 - 1] : 0.0f;
    v[5] = (j0 < 252) ? u[rb + j0 + 4] : 0.0f;
}

__device__ __forceinline__ void stencil4(const float k2[4], const float m1[4],
    const float m2[4], const float hx[4], const float hs[4], const float hy[4],
    const float vc[6], const float vn[6], const float vs[6], float rp[4])
{
    #pragma unroll
    for (int p = 0; p < 4; ++p){
        float hxx = hx[p], hyy = hy[p];
        rp[p] = (k2[p] + 2.0f*(hxx + hyy))*vc[p+1]
              + (0.5f*m1[p] - hxx)*vc[p+2]
              - (0.5f*m1[p] + hxx)*vc[p]
              + (0.5f*m2[p] - hyy)*vn[p+1]
              - (0.5f*m2[p] + hyy)*vs[p+1]
              - 0.25f*hs[p]*(vn[p+2] - vs[p+2] - vn[p] + vs[p]);
    }
}

// ---------------------------------------------------------------------------
// K2: fused z = A(A(x)); r = x + z - x_prev; out += 0.5*sum(D r^2).
// Block: 16-row strip x 256 cols of one (b,t) image. y kept in LDS (18 rows
// incl. halo, recomputed per strip).
// ---------------------------------------------------------------------------
#define YSW 268
__global__ __launch_bounds__(256) void fused_A(
    const float* __restrict__ x, const _Float16* __restrict__ fld,
    float* __restrict__ out)
{
    __shared__ float ys[18*YSW];
    __shared__ float red[256];

    const int tid = threadIdx.x;
    const int cg  = tid & 63;            // col group (4 cols)
    const int rw  = tid >> 6;            // row within pass
    const int jc  = cg << 2;
    const int bt  = blockIdx.y;          // 0..31
    const int t   = bt & 7;
    const int i0  = blockIdx.x << 4;

    // zero halo columns (j=-1 -> idx 3, j=256 -> idx 260)
    if (tid < 18){ ys[tid*YSW + 3] = 0.0f; ys[tid*YSW + 260] = 0.0f; }

    // ---- phase 1: y = A(x) on rows i0-1 .. i0+16 ----
    for (int p = 0; p < 5; ++p){
        int yr = p*4 + rw;               // wave-uniform branch
        if (yr < 18){
            int iy = i0 - 1 + yr;
            float y[4] = {0,0,0,0};
            if (iy >= 0 && iy < 256){
                int pix = (bt << 16) + (iy << 8) + jc;
                int rb  = pix - jc;
                float vc[6], vn[6], vs[6];
                row6(x, rb, jc, vc);
                if (iy < 255) row6(x, rb + 256, jc, vn);
                else { vn[0]=vn[1]=vn[2]=vn[3]=vn[4]=vn[5]=0.0f; }
                if (iy > 0) row6(x, rb - 256, jc, vs);
                else { vs[0]=vs[1]=vs[2]=vs[3]=vs[4]=vs[5]=0.0f; }
                float k2[4], m1[4], m2[4], hx[4], hs[4], hy[4];
                ldf4(&fld[0*F_ELEMS + pix], k2);
                ldf4(&fld[1*F_ELEMS + pix], m1);
                ldf4(&fld[2*F_ELEMS + pix], m2);
                ldf4(&fld[3*F_ELEMS + pix], hx);
                ldf4(&fld[4*F_ELEMS + pix], hs);
                ldf4(&fld[5*F_ELEMS + pix], hy);
                stencil4(k2, m1, m2, hx, hs, hy, vc, vn, vs, y);
            }
            float4 y4 = make_float4(y[0], y[1], y[2], y[3]);
            *(float4*)&ys[yr*YSW + 4 + jc] = y4;
        }
    }
    __syncthreads();

    // ---- phase 2: z = A(y); accumulate 0.5 * D * r^2 ----
    float local = 0.0f;
    #pragma unroll
    for (int p = 0; p < 4; ++p){
        int zr = p*4 + rw;               // 0..15
        int iz = i0 + zr;
        int pix = (bt << 16) + (iz << 8) + jc;
        int base = (zr + 1)*YSW + 4 + jc;

        float vc[6], vn[6], vs[6];
        {
            float4 c4 = *(const float4*)&ys[base];
            vc[1]=c4.x; vc[2]=c4.y; vc[3]=c4.z; vc[4]=c4.w;
            vc[0]=ys[base-1]; vc[5]=ys[base+4];
            float4 n4 = *(const float4*)&ys[base+YSW];
            vn[1]=n4.x; vn[2]=n4.y; vn[3]=n4.z; vn[4]=n4.w;
            vn[0]=ys[base+YSW-1]; vn[5]=ys[base+YSW+4];
            float4 s4 = *(const float4*)&ys[base-YSW];
            vs[1]=s4.x; vs[2]=s4.y; vs[3]=s4.z; vs[4]=s4.w;
            vs[0]=ys[base-YSW-1]; vs[5]=ys[base-YSW+4];
        }
        float k2[4], m1[4], m2[4], hx[4], hs[4], hy[4], dv[4], z[4];
        ldf4(&fld[0*F_ELEMS + pix], k2);
        ldf4(&fld[1*F_ELEMS + pix], m1);
        ldf4(&fld[2*F_ELEMS + pix], m2);
        ldf4(&fld[3*F_ELEMS + pix], hx);
        ldf4(&fld[4*F_ELEMS + pix], hs);
        ldf4(&fld[5*F_ELEMS + pix], hy);
        ldf4(&fld[6*F_ELEMS + pix], dv);
        stencil4(k2, m1, m2, hx, hs, hy, vc, vn, vs, z);

        float4 xc = *(const float4*)&x[pix];
        float4 xp = make_float4(0,0,0,0);
        if (t > 0) xp = *(const float4*)&x[pix - IMG];
        const float* xcp = (const float*)&xc;
        const float* xpp = (const float*)&xp;
        #pragma unroll
        for (int q = 0; q < 4; ++q){
            float r = xcp[q] + z[q] - xpp[q];
            local += dv[q]*r*r;
        }
    }

    red[tid] = local;
    __syncthreads();
    for (int s = 128; s > 0; s >>= 1){
        if (tid < s) red[tid] += red[tid + s];
        __syncthreads();
    }
    if (tid == 0) atomicAdd(out, 0.5f*red[0]);
}

extern "C" void kernel_launch(void* const* d_in, const int* in_sizes, int n_in,
                              void* d_out, int out_size, void* d_ws, size_t ws_size,
                              hipStream_t stream)
{
    const float* x = (const float*)d_in[0];
    const float* w = (const float*)d_in[1];
    float* out = (float*)d_out;
    _Float16* fld = (_Float16*)d_ws;

    zero_out<<<1, 1, 0, stream>>>(out);
    conv_mfma<<<dim3(128, 4), 256, 0, stream>>>(x, w, fld, out);
    fused_A<<<dim3(16, 32), 256, 0, stream>>>(x, fld, out);
}